// Round 5
// baseline (1344.078 us; speedup 1.0000x reference)
//
#include <hip/hip_runtime.h>

// HypothesisDecoder, split-phase MFMA version.
//  prep:   vols -> channel-last fp16 (64-cell tile transpose, coalesced b128 writes)
//          weights -> MFMA B-fragment order
//  gather: LDS-free, 1 query x 4 ch-slice threads, 16 waves/CU -> F[q][320] fp16 in ws
//  conv:   per 512-thr block GPTS=3 points, F staged to LDS (PITCH=328, b128 A-reads),
//          3x conv1d(k3) as tap-major GEMM on v_mfma_f32_32x32x16_f16 + BN/ReLU,
//          conv3 + softmax on VALU.  Chunked over points to fit ws.

typedef _Float16 half8 __attribute__((ext_vector_type(8)));
typedef float floatx16 __attribute__((ext_vector_type(16)));

#define NPTS  8192
#define HH    32
#define GPTS  3
#define PITCH 328        // halves; 656B row stride, 16B-aligned
#define ROWS  34
#define S1    110592     // 48^3
#define S0    13824      // 24^3
#define EPSF  1e-5f

// ---------- prep: vol [B][128][S] fp32 -> [B][S][128] fp16, 64-cell tiles ----------
__global__ __launch_bounds__(256) void tvol2(const float* __restrict__ in,
                                             ushort* __restrict__ out, int S) {
    __shared__ uint t[64][65];                 // [cell][ch-pair], pitch 65 words
    const int b  = blockIdx.y;
    const int s0 = blockIdx.x * 64;
    const int tid = threadIdx.x;
    const int l = tid & 63, cp0 = tid >> 6;    // lane = cell, cp = channel-pair group
#pragma unroll
    for (int rep = 0; rep < 16; ++rep) {
        int cpi = cp0 + 4 * rep;               // pair index 0..63
        int c0 = 2 * cpi;
        float x0 = in[((size_t)b * 128 + c0) * S + s0 + l];
        float x1 = in[((size_t)b * 128 + c0 + 1) * S + s0 + l];
        ushort u0 = __builtin_bit_cast(ushort, (_Float16)x0);
        ushort u1 = __builtin_bit_cast(ushort, (_Float16)x1);
        t[l][cpi] = (uint)u0 | ((uint)u1 << 16);
    }
    __syncthreads();
    const int s = tid >> 2, qd = tid & 3;      // cell, quarter (32 ch)
    uint4* op = (uint4*)(out + ((size_t)b * S + s0 + s) * 128 + qd * 32);
#pragma unroll
    for (int j = 0; j < 4; ++j) {
        uint4 v;
        v.x = t[s][qd * 16 + 4 * j + 0];
        v.y = t[s][qd * 16 + 4 * j + 1];
        v.z = t[s][qd * 16 + 4 * j + 2];
        v.w = t[s][qd * 16 + 4 * j + 3];
        op[j] = v;
    }
}

// ---------- prep: weights (O=256,I,3) -> MFMA B-fragment order ----------
// dst[(((kc*8 + nt)*64 + lane)*8 + j)] = fp16( w[o][i][t] )
__global__ void wprep(const float* __restrict__ w, ushort* __restrict__ dst, int I, int KC) {
    int tid = blockIdx.x * 256 + threadIdx.x;
    if (tid >= KC * 4096) return;
    int j    = tid & 7;
    int lane = (tid >> 3) & 63;
    int nt   = (tid >> 9) & 7;
    int kc   = tid >> 12;
    int I16  = I / 16;
    int o    = nt * 32 + (lane & 31);
    int t    = kc / I16;
    int iw   = (kc % I16) * 16 + (lane >> 5) * 8 + j;
    float v  = w[((size_t)o * I + iw) * 3 + t];
    dst[tid] = __builtin_bit_cast(ushort, (_Float16)v);
}

// ---------- helpers ----------
__device__ __forceinline__ void setup_corners(float px, float py, float pz, int D,
                                              int* __restrict__ idx, float* __restrict__ wt) {
    float cx = px * (D - 1), cy = py * (D - 1), cz = pz * (D - 1);
    float fx = floorf(cx), fy = floorf(cy), fz = floorf(cz);
    float rx = cx - fx, ry = cy - fy, rz = cz - fz;
    int ix = (int)fx, iy = (int)fy, iz = (int)fz;
#pragma unroll
    for (int k = 0; k < 8; ++k) {
        int dx = k >> 2, dy = (k >> 1) & 1, dz = k & 1;
        int jx = ix + dx, jy = iy + dy, jz = iz + dz;
        bool valid = (jx >= 0) && (jx < D) && (jy >= 0) && (jy < D) && (jz >= 0) && (jz < D);
        int cxi = min(max(jx, 0), D - 1), cyi = min(max(jy, 0), D - 1), czi = min(max(jz, 0), D - 1);
        float w = (dx ? rx : 1.f - rx) * (dy ? ry : 1.f - ry) * (dz ? rz : 1.f - rz);
        idx[k] = (cxi * D + cyi) * D + czi;
        wt[k]  = valid ? w : 0.f;
    }
}

__device__ __forceinline__ uint packh2(float a, float b) {
    ushort ua = __builtin_bit_cast(ushort, (_Float16)a);
    ushort ub = __builtin_bit_cast(ushort, (_Float16)b);
    return (uint)ua | ((uint)ub << 16);
}

__device__ __forceinline__ half8 lda16(const ushort* p) {
    uint4 u = *(const uint4*)p;
    return __builtin_bit_cast(half8, u);
}

// ---------- gather: 1 query x 4 ch-slice threads -> Fg[qrel][320] fp16 ----------
__global__ __launch_bounds__(256, 4) void gather_kernel(
    const float* __restrict__ pts, const float* __restrict__ pf,
    const int* __restrict__ pbatch,
    const ushort* __restrict__ v1t, const ushort* __restrict__ v0t,
    ushort* __restrict__ Fg, int q0)
{
    const int gid  = blockIdx.x * 256 + threadIdx.x;
    const int qrel = gid >> 2, cj = gid & 3;
    const int q    = q0 + qrel;
    const int n    = q >> 5;

    const float* pp = pts + (size_t)q * 3;
    const float px = pp[0], py = pp[1], pz = pp[2];
    const int bi = pbatch[n];

    int idx1[8]; float wt1[8]; setup_corners(px, py, pz, 48, idx1, wt1);
    int idx0[8]; float wt0[8]; setup_corners(px, py, pz, 24, idx0, wt0);

    ushort* dq = Fg + (size_t)qrel * 320;

    // vol1 -> ch 0..127
    {
        const ushort* vb = v1t + (size_t)bi * (128ull * S1) + cj * 32;
        float acc[32];
#pragma unroll
        for (int k = 0; k < 32; ++k) acc[k] = 0.f;
#pragma unroll
        for (int c = 0; c < 8; ++c) {
            const ushort* p = vb + (size_t)idx1[c] * 128;
            float w = wt1[c];
#pragma unroll
            for (int qd = 0; qd < 4; ++qd) {
                half8 x = lda16(p + 8 * qd);
#pragma unroll
                for (int e = 0; e < 8; ++e) acc[qd * 8 + e] += w * (float)x[e];
            }
        }
        uint4* d = (uint4*)(dq + cj * 32);
#pragma unroll
        for (int j = 0; j < 4; ++j) {
            uint4 u;
            u.x = packh2(acc[8 * j + 0], acc[8 * j + 1]);
            u.y = packh2(acc[8 * j + 2], acc[8 * j + 3]);
            u.z = packh2(acc[8 * j + 4], acc[8 * j + 5]);
            u.w = packh2(acc[8 * j + 6], acc[8 * j + 7]);
            d[j] = u;
        }
    }
    // vol0 -> ch 128..255
    {
        const ushort* vb = v0t + (size_t)bi * (128ull * S0) + cj * 32;
        float acc[32];
#pragma unroll
        for (int k = 0; k < 32; ++k) acc[k] = 0.f;
#pragma unroll
        for (int c = 0; c < 8; ++c) {
            const ushort* p = vb + (size_t)idx0[c] * 128;
            float w = wt0[c];
#pragma unroll
            for (int qd = 0; qd < 4; ++qd) {
                half8 x = lda16(p + 8 * qd);
#pragma unroll
                for (int e = 0; e < 8; ++e) acc[qd * 8 + e] += w * (float)x[e];
            }
        }
        uint4* d = (uint4*)(dq + 128 + cj * 32);
#pragma unroll
        for (int j = 0; j < 4; ++j) {
            uint4 u;
            u.x = packh2(acc[8 * j + 0], acc[8 * j + 1]);
            u.y = packh2(acc[8 * j + 2], acc[8 * j + 3]);
            u.z = packh2(acc[8 * j + 4], acc[8 * j + 5]);
            u.w = packh2(acc[8 * j + 6], acc[8 * j + 7]);
            d[j] = u;
        }
    }
    // pts_feat -> ch 256..319
    {
        const float* pfp = pf + (size_t)q * 64 + cj * 16;
        uint4* d = (uint4*)(dq + 256 + cj * 16);
#pragma unroll
        for (int j = 0; j < 2; ++j) {
            float4 a = ((const float4*)pfp)[2 * j];
            float4 b = ((const float4*)pfp)[2 * j + 1];
            uint4 u;
            u.x = packh2(a.x, a.y); u.y = packh2(a.z, a.w);
            u.z = packh2(b.x, b.y); u.w = packh2(b.z, b.w);
            d[j] = u;
        }
    }
}

// ---------- conv layer: GEMM M=96, N=256 (8 waves x 32), K=3*16*I16 ----------
template <int I16>
__device__ __forceinline__ void conv_layer(
    ushort (&F)[GPTS][ROWS][PITCH], const ushort* __restrict__ wf,
    const float* __restrict__ gg, const float* __restrict__ bb,
    const float* __restrict__ mm, const float* __restrict__ vv,
    int wv, int lane)
{
    constexpr int KC = 3 * I16;
    const int ch = wv * 32 + (lane & 31);
    const float sc = gg[ch] / sqrtf(vv[ch] + EPSF);
    const float bs = bb[ch] - mm[ch] * sc;

    floatx16 acc[GPTS];
#pragma unroll
    for (int p = 0; p < GPTS; ++p)
#pragma unroll
        for (int r = 0; r < 16; ++r) acc[p][r] = 0.f;

    const ushort* aB = &F[0][0][0] + (lane & 31) * PITCH + (lane >> 5) * 8;
    const ushort* bB = wf + (size_t)wv * 512 + (size_t)lane * 8;

    half8 p0 = *(const half8*)(bB);
    half8 p1 = *(const half8*)(bB + 1 * 4096);
    half8 p2 = *(const half8*)(bB + 2 * 4096);
    half8 p3 = *(const half8*)(bB + 3 * 4096);

    int t = 0, ic = 0;
#define STEP(BREG, KNEXT)                                                           \
    {                                                                               \
        const ushort* ap = aB + t * PITCH + ic * 16;                                \
        half8 a0 = lda16(ap);                                                       \
        half8 a1 = lda16(ap + 1 * ROWS * PITCH);                                    \
        half8 a2 = lda16(ap + 2 * ROWS * PITCH);                                    \
        acc[0] = __builtin_amdgcn_mfma_f32_32x32x16_f16(a0, BREG, acc[0], 0, 0, 0); \
        acc[1] = __builtin_amdgcn_mfma_f32_32x32x16_f16(a1, BREG, acc[1], 0, 0, 0); \
        acc[2] = __builtin_amdgcn_mfma_f32_32x32x16_f16(a2, BREG, acc[2], 0, 0, 0); \
        BREG = *(const half8*)(bB + (size_t)min(KNEXT, KC - 1) * 4096);             \
        if (++ic == I16) { ic = 0; ++t; }                                           \
    }

#pragma unroll 1
    for (int kc = 0; kc < KC; kc += 4) {
        STEP(p0, kc + 4)
        STEP(p1, kc + 5)
        STEP(p2, kc + 6)
        STEP(p3, kc + 7)
    }
#undef STEP

    __syncthreads();   // all waves done READING F
#pragma unroll
    for (int p = 0; p < GPTS; ++p)
#pragma unroll
        for (int r = 0; r < 16; ++r) {
            int h = (r & 3) + 8 * (r >> 2) + 4 * (lane >> 5);
            float v = fmaxf(fmaf(acc[p][r], sc, bs), 0.f);
            F[p][h + 1][ch] = __builtin_bit_cast(ushort, (_Float16)v);
        }
    __syncthreads();
}

// ---------- conv kernel: GPTS=3 pts/block, F from ws ----------
__global__ __launch_bounds__(512, 4) void conv_kernel(
    const ushort* __restrict__ Fg,
    const ushort* __restrict__ wf0, const ushort* __restrict__ wf1,
    const ushort* __restrict__ wf2,
    const float* __restrict__ w3, const float* __restrict__ b3,
    const float* __restrict__ g0, const float* __restrict__ be0,
    const float* __restrict__ m0, const float* __restrict__ va0,
    const float* __restrict__ g1, const float* __restrict__ be1,
    const float* __restrict__ m1, const float* __restrict__ va1,
    const float* __restrict__ g2, const float* __restrict__ be2,
    const float* __restrict__ m2, const float* __restrict__ va2,
    float* __restrict__ outp, int startPt, int chunkPts)
{
    __shared__ __align__(16) ushort F[GPTS][ROWS][PITCH];   // 66912 B
    __shared__ float w3s[768];

    const int tid = threadIdx.x, lane = tid & 63, wv = tid >> 6;
    const int p0 = blockIdx.x * GPTS;

    if (tid < 256) {
        w3s[tid]       = w3[tid];
        w3s[256 + tid] = w3[256 + tid];
        w3s[512 + tid] = w3[512 + tid];
    }
    // zero pad rows 0 and 33 (164 uints per row, 6 rows)
    for (int i = tid; i < 984; i += 512) {
        int pt = i / 328, rr = (i % 328) / 164, c = i % 164;
        ((uint*)&F[pt][rr ? 33 : 0][0])[c] = 0u;
    }
    // stage 96 queries x 640B from Fg (clamped at chunk tail)
    for (int i = tid; i < 3840; i += 512) {
        int ql = i / 40, k = i % 40;
        int ptl = min(p0 + (ql >> 5), chunkPts - 1);
        const uint4* src = (const uint4*)(Fg + ((size_t)ptl * 32 + (ql & 31)) * 320 + k * 8);
        *(uint4*)&F[ql >> 5][(ql & 31) + 1][k * 8] = *src;
    }
    __syncthreads();

    conv_layer<20>(F, wf0, g0, be0, m0, va0, wv, lane);
    conv_layer<16>(F, wf1, g1, be1, m1, va1, wv, lane);
    conv_layer<16>(F, wf2, g2, be2, m2, va2, wv, lane);

    // conv3 (256->1) + softmax over 32 hyps
    if (wv < GPTS) {
        const int hh = lane & 31, ihalf = lane >> 5;
        float a = 0.f;
#pragma unroll
        for (int t = 0; t < 3; ++t) {
            const ushort* fr = &F[wv][hh + t][ihalf * 128];
#pragma unroll
            for (int b8 = 0; b8 < 16; ++b8) {
                half8 x = lda16(fr + b8 * 8);
                int i0 = ihalf * 128 + b8 * 8;
#pragma unroll
                for (int j = 0; j < 8; ++j)
                    a += (float)x[j] * w3s[(i0 + j) * 3 + t];
            }
        }
        a += __shfl_xor(a, 32, 64);
        a += b3[0];
        float mx = a;
#pragma unroll
        for (int m = 16; m >= 1; m >>= 1) mx = fmaxf(mx, __shfl_xor(mx, m, 64));
        float e = expf(a - mx);
        float s = e;
#pragma unroll
        for (int m = 16; m >= 1; m >>= 1) s += __shfl_xor(s, m, 64);
        if (lane < 32) {
            int n = startPt + min(p0 + wv, chunkPts - 1);
            outp[(size_t)n * HH + hh] = e / s;
        }
    }
}

extern "C" void kernel_launch(void* const* d_in, const int* in_sizes, int n_in,
                              void* d_out, int out_size, void* d_ws, size_t ws_size,
                              hipStream_t stream) {
    const float* pts      = (const float*)d_in[0];
    const float* pts_feat = (const float*)d_in[1];
    const int*   pbatch   = (const int*)d_in[2];
    const float* vol0     = (const float*)d_in[3];
    const float* vol1     = (const float*)d_in[4];
    const float* w0 = (const float*)d_in[5];
    const float* w1 = (const float*)d_in[6];
    const float* w2 = (const float*)d_in[7];
    const float* w3 = (const float*)d_in[8];
    const float* b3 = (const float*)d_in[9];
    const float* g0 = (const float*)d_in[10];
    const float* be0 = (const float*)d_in[11];
    const float* m0 = (const float*)d_in[12];
    const float* va0 = (const float*)d_in[13];
    const float* g1 = (const float*)d_in[14];
    const float* be1 = (const float*)d_in[15];
    const float* m1 = (const float*)d_in[16];
    const float* va1 = (const float*)d_in[17];
    const float* g2 = (const float*)d_in[18];
    const float* be2 = (const float*)d_in[19];
    const float* m2 = (const float*)d_in[20];
    const float* va2 = (const float*)d_in[21];
    float* outp = (float*)d_out;

    // ws layout (ushort units)
    const size_t o_v1 = 0;
    const size_t s_v1 = 4ull * S1 * 128;
    const size_t o_v0 = o_v1 + s_v1;
    const size_t s_v0 = 4ull * S0 * 128;
    const size_t o_w0 = o_v0 + s_v0;
    const size_t s_w0 = 60ull * 4096;
    const size_t o_w1 = o_w0 + s_w0;
    const size_t s_w1 = 48ull * 4096;
    const size_t o_w2 = o_w1 + s_w1;
    const size_t s_w2 = 48ull * 4096;
    const size_t o_fg = o_w2 + s_w2;

    // pick chunk count: Fg chunk = (NPTS/chunks)*32*320 halves
    int chunks = 0;
    for (int k = 1; k <= 32; k <<= 1) {
        size_t fg = ((size_t)NPTS / k) * 32 * 320;
        if ((o_fg + fg) * 2 <= ws_size) { chunks = k; break; }
    }
    if (!chunks) return;

    ushort* wsu = (ushort*)d_ws;
    ushort* v1t = wsu + o_v1;
    ushort* v0t = wsu + o_v0;
    ushort* wf0 = wsu + o_w0;
    ushort* wf1 = wsu + o_w1;
    ushort* wf2 = wsu + o_w2;
    ushort* Fg  = wsu + o_fg;

    tvol2<<<dim3(S1 / 64, 4), 256, 0, stream>>>(vol1, v1t, S1);
    tvol2<<<dim3(S0 / 64, 4), 256, 0, stream>>>(vol0, v0t, S0);
    wprep<<<(int)((60 * 4096 + 255) / 256), 256, 0, stream>>>(w0, wf0, 320, 60);
    wprep<<<(int)((48 * 4096 + 255) / 256), 256, 0, stream>>>(w1, wf1, 256, 48);
    wprep<<<(int)((48 * 4096 + 255) / 256), 256, 0, stream>>>(w2, wf2, 256, 48);

    const int chunkPts = NPTS / chunks;
    const int nq = chunkPts * HH;
    const int gatherBlocks = nq / 64;                    // 4 thr/query, 256 thr/blk
    const int convBlocks = (chunkPts + GPTS - 1) / GPTS;
    for (int c = 0; c < chunks; ++c) {
        const int startPt = c * chunkPts;
        gather_kernel<<<gatherBlocks, 256, 0, stream>>>(
            pts, pts_feat, pbatch, v1t, v0t, Fg, startPt * HH);
        conv_kernel<<<convBlocks, 512, 0, stream>>>(
            Fg, wf0, wf1, wf2, w3, b3,
            g0, be0, m0, va0, g1, be1, m1, va1, g2, be2, m2, va2,
            outp, startPt, chunkPts);
    }
}